// Round 5
// baseline (1023.146 us; speedup 1.0000x reference)
//
#include <hip/hip_runtime.h>
#include <math.h>

// B=8, W=H=128, D=64, bs=4 -> M=N=8192 rows, F=1024 features.
// R5: hi-only fp16 GEMM (K=1024). x = xhi + xlo (fp16); sim ~= xhi*yhi.
// Dropped cross terms err std ~1.7e-5, max ~7e-5 << EPS=3e-4 refine window.
// Top-3 tracking + exact fp64 refine of flagged rows keeps argmax exact.
// simKernel: 256x256 block tile, 4 waves 2x2, 128x128 per wave (8x8 frags),
// BK=32 LDS double-buffer with XOR bank swizzle (64 KiB), register-staged
// global prefetch, 8x8 supertile grid swizzle.

#define NROWS 8192
#define KY 1024
#define NCH 64     // col partial chunks (32 col tiles * 2 wave-cols)
#define EPS 3e-4f

typedef _Float16 v8h __attribute__((ext_vector_type(8)));
typedef float f32x4 __attribute__((ext_vector_type(4)));

// One 64-lane wave per feature-row; 16 floats/lane; shuffle-only reductions.
__global__ __launch_bounds__(256) void normSplitKernel(
    const float* __restrict__ x, const float* __restrict__ y,
    _Float16* __restrict__ Xh, _Float16* __restrict__ Xl,
    _Float16* __restrict__ Yh, _Float16* __restrict__ Yl,
    int* __restrict__ flagCnt) {
    if (blockIdx.x == 0 && threadIdx.x == 0) *flagCnt = 0;
    int gr = blockIdx.x * 4 + (threadIdx.x >> 6);   // 0..16383
    int ln = threadIdx.x & 63;
    bool isX = gr < NROWS;
    int row = isX ? gr : gr - NROWS;
    const float* src = isX ? x : y;
    _Float16* dh = isX ? Xh : Yh;
    _Float16* dl = isX ? Xl : Yl;
    int b = row >> 10, wq = (row >> 5) & 31, hq = row & 31;
    int a = ln >> 4, c = (ln >> 2) & 3, d0 = (ln & 3) << 4;
    const float* p = &src[(((size_t)(b * 128) + wq * 4 + a) * 128 + hq * 4 + c) * 64 + d0];
    float vv[16];
    *(float4*)(vv + 0)  = *(const float4*)(p + 0);
    *(float4*)(vv + 4)  = *(const float4*)(p + 4);
    *(float4*)(vv + 8)  = *(const float4*)(p + 8);
    *(float4*)(vv + 12) = *(const float4*)(p + 12);
    double s = 0.0;
    #pragma unroll
    for (int q = 0; q < 16; q++) s += (double)vv[q];
    #pragma unroll
    for (int m = 1; m < 64; m <<= 1) s += __shfl_xor(s, m, 64);
    double mean = s * (1.0 / 1024.0);
    double ss = 0.0;
    #pragma unroll
    for (int q = 0; q < 16; q++) {
        double d = (double)vv[q] - mean;
        ss += d * d;
    }
    #pragma unroll
    for (int m = 1; m < 64; m <<= 1) ss += __shfl_xor(ss, m, 64);
    double scale = 1.0 / (sqrt(ss) + 1e-5);
    _Float16 hi[16], lo[16];
    #pragma unroll
    for (int q = 0; q < 16; q++) {
        float f = (float)(((double)vv[q] - mean) * scale);
        _Float16 h = (_Float16)f;
        hi[q] = h;
        lo[q] = (_Float16)(f - (float)h);
    }
    size_t f0 = (size_t)row * KY + (ln << 4);
    *(v8h*)&dh[f0]     = *(v8h*)(hi);
    *(v8h*)&dh[f0 + 8] = *(v8h*)(hi + 8);
    *(v8h*)&dl[f0]     = *(v8h*)(lo);
    *(v8h*)&dl[f0 + 8] = *(v8h*)(lo + 8);
}

// top-3 insert, strict > (ties resolved later by the exact refine pass)
#define INS3(v, ix) do {                                                    \
    if ((v) > v1) { v3 = v2; i3 = i2; v2 = v1; i2 = i1; v1 = (v); i1 = (ix);} \
    else if ((v) > v2) { v3 = v2; i3 = i2; v2 = (v); i2 = (ix); }           \
    else if ((v) > v3) { v3 = (v); i3 = (ix); }                             \
} while (0)

// MFMA GEMM C = Xh * Yh^T (K=1024) fused per-row top-3 argmax.
// 256x256 tile, 4 waves 2x2, wave tile 128x128 (8x8 frags of 16x16x32 f16).
__global__ __launch_bounds__(256, 1) void simKernel(
    const _Float16* __restrict__ Xh, const _Float16* __restrict__ Yh,
    float* __restrict__ pV1, float* __restrict__ pV2, float* __restrict__ pV3,
    int* __restrict__ pI1, int* __restrict__ pI2, int* __restrict__ pI3) {
    __shared__ _Float16 As[2][256 * 32];   // 16 KiB per buf
    __shared__ _Float16 Bs[2][256 * 32];
    const int t = threadIdx.x;
    const int l = t & 63, w = t >> 6;
    const int quad = l >> 4, lm = l & 15;
    const int wrb = (w >> 1) * 128, wcb = (w & 1) * 128;
    // 8x8 supertile swizzle over the 32x32 block grid
    const int g = blockIdx.x;
    const int sg = g >> 6, in = g & 63;
    const int bx = (sg >> 2) * 8 + (in >> 3);
    const int by = (sg & 3) * 8 + (in & 7);
    const int r0 = bx * 256, c0 = by * 256;

    f32x4 acc[8][8];
    #pragma unroll
    for (int i = 0; i < 8; i++)
        #pragma unroll
        for (int j = 0; j < 8; j++) acc[i][j] = (f32x4){0.f, 0.f, 0.f, 0.f};

    const _Float16* srcA = Xh + (size_t)(r0 + t) * KY;
    const _Float16* srcB = Yh + (size_t)(c0 + t) * KY;
    const int swz = (t >> 1) & 3;          // write-side bank swizzle
    const int wbase = t * 32;

    // prologue: slab 0 -> buffer 0
    {
        uint4 pa[4], pb[4];
        #pragma unroll
        for (int q = 0; q < 4; q++) {
            pa[q] = *(const uint4*)(srcA + q * 8);
            pb[q] = *(const uint4*)(srcB + q * 8);
        }
        #pragma unroll
        for (int q = 0; q < 4; q++) {
            *(uint4*)&As[0][wbase + ((q ^ swz) << 3)] = pa[q];
            *(uint4*)&Bs[0][wbase + ((q ^ swz) << 3)] = pb[q];
        }
    }
    __syncthreads();

    const int rsw = (lm >> 1) & 3;         // read-side row swizzle
    const int aoff = (wrb + lm) * 32 + ((quad ^ rsw) << 3);
    const int boff = (wcb + lm) * 32 + ((quad ^ rsw) << 3);

    #pragma unroll 1
    for (int s = 0; s < 32; s++) {
        const int cur = s & 1;
        uint4 pa[4], pb[4];
        if (s < 31) {
            const int kn = (s + 1) * 32;
            #pragma unroll
            for (int q = 0; q < 4; q++) {
                pa[q] = *(const uint4*)(srcA + kn + q * 8);
                pb[q] = *(const uint4*)(srcB + kn + q * 8);
            }
        }
        v8h af[8], bf[8];
        #pragma unroll
        for (int i = 0; i < 8; i++) af[i] = *(const v8h*)&As[cur][aoff + i * 512];
        #pragma unroll
        for (int j = 0; j < 8; j++) bf[j] = *(const v8h*)&Bs[cur][boff + j * 512];
        #pragma unroll
        for (int i = 0; i < 8; i++)
            #pragma unroll
            for (int j = 0; j < 8; j++)
                acc[i][j] = __builtin_amdgcn_mfma_f32_16x16x32_f16(af[i], bf[j], acc[i][j], 0, 0, 0);
        if (s < 31) {
            const int nb = cur ^ 1;
            #pragma unroll
            for (int q = 0; q < 4; q++) {
                *(uint4*)&As[nb][wbase + ((q ^ swz) << 3)] = pa[q];
                *(uint4*)&Bs[nb][wbase + ((q ^ swz) << 3)] = pb[q];
            }
            __syncthreads();
        }
    }

    // Epilogue: per-row top-3. C layout: col=lane&15, row=quad*4+reg.
    const int cch = by * 2 + (w & 1);
    const int cbase = c0 + wcb + lm;
    #pragma unroll
    for (int i = 0; i < 8; i++) {
        #pragma unroll
        for (int r = 0; r < 4; r++) {
            float v1 = -1e30f, v2 = -1e30f, v3 = -1e30f;
            int i1 = 0x7fffffff, i2 = 0x7fffffff, i3 = 0x7fffffff;
            #pragma unroll
            for (int j = 0; j < 8; j++) {
                float v = acc[i][j][r];
                int cc = cbase + j * 16;
                INS3(v, cc);
            }
            #pragma unroll
            for (int m = 1; m < 16; m <<= 1) {
                float ov1 = __shfl_xor(v1, m, 64); int oi1 = __shfl_xor(i1, m, 64);
                float ov2 = __shfl_xor(v2, m, 64); int oi2 = __shfl_xor(i2, m, 64);
                float ov3 = __shfl_xor(v3, m, 64); int oi3 = __shfl_xor(i3, m, 64);
                INS3(ov1, oi1);
                INS3(ov2, oi2);
                INS3(ov3, oi3);
            }
            if (lm == 0) {
                size_t row = (size_t)cch * NROWS + (r0 + wrb + i * 16 + quad * 4 + r);
                pV1[row] = v1; pV2[row] = v2; pV3[row] = v3;
                pI1[row] = i1; pI2[row] = i2; pI3[row] = i3;
            }
        }
    }
}

__global__ __launch_bounds__(256) void reduceKernel(
    const float* __restrict__ pV1, const float* __restrict__ pV2,
    const float* __restrict__ pV3, const int* __restrict__ pI1,
    const int* __restrict__ pI2, const int* __restrict__ pI3,
    int* __restrict__ bestIdx, int* __restrict__ flagRows,
    int* __restrict__ flagC2, int* __restrict__ flagC3,
    int* __restrict__ flagCnt, float* __restrict__ blkSum) {
    int t = threadIdx.x;
    int row = blockIdx.x * 256 + t;
    float v1 = -1e30f, v2 = -1e30f, v3 = -1e30f;
    int i1 = 0x7fffffff, i2 = 0x7fffffff, i3 = 0x7fffffff;
    for (int c = 0; c < NCH; c++) {
        size_t o = (size_t)c * NROWS + row;
        float a1 = pV1[o], a2 = pV2[o], a3 = pV3[o];
        int b1 = pI1[o], b2 = pI2[o], b3 = pI3[o];
        INS3(a1, b1);
        INS3(a2, b2);
        INS3(a3, b3);
    }
    bestIdx[row] = i1;
    if (v1 - v2 < EPS) {
        int s = atomicAdd(flagCnt, 1);
        flagRows[s] = row; flagC2[s] = i2; flagC3[s] = i3;
    }
    double sum = 1.0 - (double)v1;
    __shared__ double sh[4];
    #pragma unroll
    for (int off = 32; off; off >>= 1) sum += __shfl_down(sum, off, 64);
    if ((t & 63) == 0) sh[t >> 6] = sum;
    __syncthreads();
    if (t == 0) blkSum[blockIdx.x] = (float)(sh[0] + sh[1] + sh[2] + sh[3]);
}

// Exact fp64 re-check of top-3 candidates for near-tie rows; one wave per row.
__global__ __launch_bounds__(256) void refineKernel(
    const _Float16* __restrict__ Xh, const _Float16* __restrict__ Xl,
    const _Float16* __restrict__ Yh, const _Float16* __restrict__ Yl,
    int* __restrict__ bestIdx, const int* __restrict__ flagRows,
    const int* __restrict__ flagC2, const int* __restrict__ flagC3,
    const int* __restrict__ flagCnt) {
    int n = *flagCnt;
    int wave = (blockIdx.x << 2) + (threadIdx.x >> 6);
    int ln = threadIdx.x & 63;
    for (int fi = wave; fi < n; fi += gridDim.x * 4) {
        int row = flagRows[fi];
        int cand[3];
        cand[0] = bestIdx[row]; cand[1] = flagC2[fi]; cand[2] = flagC3[fi];
        double d[3];
        #pragma unroll
        for (int c = 0; c < 3; c++) {
            double p = 0.0;
            int yr = cand[c];
            #pragma unroll
            for (int q = 0; q < 16; q++) {
                int k = (ln << 4) + q;
                float xv = (float)Xh[(size_t)row * KY + k] + (float)Xl[(size_t)row * KY + k];
                float yv = (float)Yh[(size_t)yr * KY + k] + (float)Yl[(size_t)yr * KY + k];
                p += (double)xv * yv;
            }
            #pragma unroll
            for (int m = 1; m < 64; m <<= 1) p += __shfl_xor(p, m, 64);
            d[c] = p;
        }
        if (ln == 0) {
            int bi = cand[0]; double bv = d[0];
            #pragma unroll
            for (int c = 1; c < 3; c++) {
                if (d[c] > bv || (d[c] == bv && cand[c] < bi)) { bv = d[c]; bi = cand[c]; }
            }
            bestIdx[row] = bi;
        }
    }
}

// new_x gather (hi+lo reconstruct ~ fp32 codebook) + loss finalize.
__global__ __launch_bounds__(256) void gatherKernel(
    const _Float16* __restrict__ Yh, const _Float16* __restrict__ Yl,
    const int* __restrict__ bestIdx, const float* __restrict__ blkSum,
    float* __restrict__ out) {
    int t = threadIdx.x;
    if (blockIdx.x == 0 && t == 0) {
        double s = 0.0;
        for (int i = 0; i < 32; i++) s += (double)blkSum[i];
        out[0] = (float)(s / 8192.0);
    }
    int g = (blockIdx.x * 256 + t) << 2;
    int b = g >> 20, wq = (g >> 13) & 127, hq = (g >> 6) & 127, d = g & 63;
    int row = (b << 10) + ((wq >> 2) << 5) + (hq >> 2);
    int f = ((wq & 3) << 8) + ((hq & 3) << 6) + d;
    size_t base = (size_t)bestIdx[row] * KY + f;
    const _Float16* ph = &Yh[base];
    const _Float16* pl = &Yl[base];
    out[1 + g + 0] = (float)ph[0] + (float)pl[0];
    out[1 + g + 1] = (float)ph[1] + (float)pl[1];
    out[1 + g + 2] = (float)ph[2] + (float)pl[2];
    out[1 + g + 3] = (float)ph[3] + (float)pl[3];
}

extern "C" void kernel_launch(void* const* d_in, const int* in_sizes, int n_in,
                              void* d_out, int out_size, void* d_ws, size_t ws_size,
                              hipStream_t stream) {
    const float* x = (const float*)d_in[0];
    const float* y = (const float*)d_in[1];
    float* out = (float*)d_out;
    char* ws = (char*)d_ws;
    _Float16* Xh  = (_Float16*)(ws);
    _Float16* Xl  = (_Float16*)(ws + 16777216u);
    _Float16* Yh  = (_Float16*)(ws + 33554432u);
    _Float16* Yl  = (_Float16*)(ws + 50331648u);
    float* pV1    = (float*)(ws + 67108864u);
    float* pV2    = (float*)(ws + 69206016u);
    float* pV3    = (float*)(ws + 71303168u);
    int*   pI1    = (int*)  (ws + 73400320u);
    int*   pI2    = (int*)  (ws + 75497472u);
    int*   pI3    = (int*)  (ws + 77594624u);
    int* bestIdx  = (int*)  (ws + 79691776u);
    int* flagRows = (int*)  (ws + 79724544u);
    int* flagC2   = (int*)  (ws + 79757312u);
    int* flagC3   = (int*)  (ws + 79790080u);
    int* flagCnt  = (int*)  (ws + 79822848u);
    float* blkSum = (float*)(ws + 79822976u);

    normSplitKernel<<<4096, 256, 0, stream>>>(x, y, Xh, Xl, Yh, Yl, flagCnt);
    simKernel<<<1024, 256, 0, stream>>>(Xh, Yh, pV1, pV2, pV3, pI1, pI2, pI3);
    reduceKernel<<<32, 256, 0, stream>>>(pV1, pV2, pV3, pI1, pI2, pI3,
                                         bestIdx, flagRows, flagC2, flagC3, flagCnt, blkSum);
    refineKernel<<<64, 256, 0, stream>>>(Xh, Xl, Yh, Yl, bestIdx,
                                         flagRows, flagC2, flagC3, flagCnt);
    gatherKernel<<<8192, 256, 0, stream>>>(Yh, Yl, bestIdx, blkSum, out);
}

// Round 6
// 467.938 us; speedup vs baseline: 2.1865x; 2.1865x over previous
//
#include <hip/hip_runtime.h>
#include <math.h>

// B=8, W=H=128, D=64, bs=4 -> M=N=8192 rows, F=1024 features.
// R6 = R4 GEMM structure (64x64/wave, no spill) + R5 numerics (hi-only K=1024).
// x = xhi + xlo (fp16); sim ~= xhi*yhi. Dropped cross terms err std ~1.7e-5,
// max ~1e-4 << EPS=3e-4. Top-3 + exact fp64 refine keeps argmax exact.
// simKernel: 128x128 block tile, 4 waves 2x2 (64x64 per wave, acc=64 VGPRs),
// BK=32 register-staged double buffer (global->VGPR->LDS; barrier lgkm-only),
// grid transpose for L2 locality, epilogue LDS-merge -> 64 partial chunks.

#define NROWS 8192
#define KY 1024
#define NCH 64     // col partial chunks (one per 128-col tile)
#define EPS 3e-4f

typedef _Float16 v8h __attribute__((ext_vector_type(8)));
typedef float f32x4 __attribute__((ext_vector_type(4)));

// One 64-lane wave per feature-row; 16 floats/lane; shuffle-only reductions.
__global__ __launch_bounds__(256) void normSplitKernel(
    const float* __restrict__ x, const float* __restrict__ y,
    _Float16* __restrict__ Xh, _Float16* __restrict__ Xl,
    _Float16* __restrict__ Yh, _Float16* __restrict__ Yl,
    int* __restrict__ flagCnt) {
    if (blockIdx.x == 0 && threadIdx.x == 0) *flagCnt = 0;
    int gr = blockIdx.x * 4 + (threadIdx.x >> 6);   // 0..16383
    int ln = threadIdx.x & 63;
    bool isX = gr < NROWS;
    int row = isX ? gr : gr - NROWS;
    const float* src = isX ? x : y;
    _Float16* dh = isX ? Xh : Yh;
    _Float16* dl = isX ? Xl : Yl;
    int b = row >> 10, wq = (row >> 5) & 31, hq = row & 31;
    int a = ln >> 4, c = (ln >> 2) & 3, d0 = (ln & 3) << 4;
    const float* p = &src[(((size_t)(b * 128) + wq * 4 + a) * 128 + hq * 4 + c) * 64 + d0];
    float vv[16];
    *(float4*)(vv + 0)  = *(const float4*)(p + 0);
    *(float4*)(vv + 4)  = *(const float4*)(p + 4);
    *(float4*)(vv + 8)  = *(const float4*)(p + 8);
    *(float4*)(vv + 12) = *(const float4*)(p + 12);
    double s = 0.0;
    #pragma unroll
    for (int q = 0; q < 16; q++) s += (double)vv[q];
    #pragma unroll
    for (int m = 1; m < 64; m <<= 1) s += __shfl_xor(s, m, 64);
    double mean = s * (1.0 / 1024.0);
    double ss = 0.0;
    #pragma unroll
    for (int q = 0; q < 16; q++) {
        double d = (double)vv[q] - mean;
        ss += d * d;
    }
    #pragma unroll
    for (int m = 1; m < 64; m <<= 1) ss += __shfl_xor(ss, m, 64);
    double scale = 1.0 / (sqrt(ss) + 1e-5);
    _Float16 hi[16], lo[16];
    #pragma unroll
    for (int q = 0; q < 16; q++) {
        float f = (float)(((double)vv[q] - mean) * scale);
        _Float16 h = (_Float16)f;
        hi[q] = h;
        lo[q] = (_Float16)(f - (float)h);
    }
    size_t f0 = (size_t)row * KY + (ln << 4);
    *(v8h*)&dh[f0]     = *(v8h*)(hi);
    *(v8h*)&dh[f0 + 8] = *(v8h*)(hi + 8);
    *(v8h*)&dl[f0]     = *(v8h*)(lo);
    *(v8h*)&dl[f0 + 8] = *(v8h*)(lo + 8);
}

// top-3 insert, strict > (ties resolved later by the exact refine pass)
#define INS3(v, ix) do {                                                    \
    if ((v) > v1) { v3 = v2; i3 = i2; v2 = v1; i2 = i1; v1 = (v); i1 = (ix);} \
    else if ((v) > v2) { v3 = v2; i3 = i2; v2 = (v); i2 = (ix); }           \
    else if ((v) > v3) { v3 = (v); i3 = (ix); }                             \
} while (0)

// MFMA GEMM C = Xh * Yh^T (K=1024) fused per-row top-3 argmax.
// 128x128 tile, 4 waves 2x2, 64x64 per wave (4x4 frags of 16x16x32 f16).
__global__ __launch_bounds__(256) void simKernel(
    const _Float16* __restrict__ Xh, const _Float16* __restrict__ Yh,
    float* __restrict__ pV1, float* __restrict__ pV2, float* __restrict__ pV3,
    int* __restrict__ pI1, int* __restrict__ pI2, int* __restrict__ pI3) {
    __shared__ _Float16 As[2][128 * 32];
    __shared__ _Float16 Bs[2][128 * 32];
    __shared__ float sV[2][2][64][3];
    __shared__ int   sI[2][2][64][3];
    const int t = threadIdx.x;
    const int l = t & 63, w = t >> 6;
    const int wr = w >> 1, wc = w & 1;
    const int quad = l >> 4, lm = l & 15;
    // grid transpose: consecutive flat ids share the A row-tile
    const int flat = blockIdx.y * 64 + blockIdx.x;
    const int bx = flat >> 6, by = flat & 63;
    const int r0 = bx * 128, c0 = by * 128;

    f32x4 acc[4][4];
    #pragma unroll
    for (int i = 0; i < 4; i++)
        #pragma unroll
        for (int j = 0; j < 4; j++) acc[i][j] = (f32x4){0.f, 0.f, 0.f, 0.f};

    const _Float16* srcA0 = Xh + (size_t)(r0 + (t >> 2)) * KY + ((t & 3) << 3);
    const _Float16* srcA1 = srcA0 + (size_t)64 * KY;
    const _Float16* srcB0 = Yh + (size_t)(c0 + (t >> 2)) * KY + ((t & 3) << 3);
    const _Float16* srcB1 = srcB0 + (size_t)64 * KY;
    const int st8 = t * 8;

    // prologue: stage k=0 through regs into buffer 0
    {
        uint4 a0 = *(const uint4*)srcA0;
        uint4 a1 = *(const uint4*)srcA1;
        uint4 b0 = *(const uint4*)srcB0;
        uint4 b1 = *(const uint4*)srcB1;
        *(uint4*)&As[0][st8] = a0;
        *(uint4*)&As[0][2048 + st8] = a1;
        *(uint4*)&Bs[0][st8] = b0;
        *(uint4*)&Bs[0][2048 + st8] = b1;
    }
    __syncthreads();

    const int offA0 = (wr * 64 + lm) * 32 + quad * 8;
    const int offB0 = (wc * 64 + lm) * 32 + quad * 8;

    #pragma unroll 1
    for (int kk = 0; kk < KY - 32; kk += 32) {
        const int cur = (kk >> 5) & 1, nxt = cur ^ 1;
        const int kn = kk + 32;
        // prefetch next k-step into registers (vmcnt pending through compute)
        uint4 na0 = *(const uint4*)(srcA0 + kn);
        uint4 na1 = *(const uint4*)(srcA1 + kn);
        uint4 nb0 = *(const uint4*)(srcB0 + kn);
        uint4 nb1 = *(const uint4*)(srcB1 + kn);
        // compute on current buffer
        v8h af[4], bf[4];
        #pragma unroll
        for (int i = 0; i < 4; i++)
            af[i] = *(const v8h*)&As[cur][offA0 + i * 512];
        #pragma unroll
        for (int j = 0; j < 4; j++)
            bf[j] = *(const v8h*)&Bs[cur][offB0 + j * 512];
        #pragma unroll
        for (int i = 0; i < 4; i++)
            #pragma unroll
            for (int j = 0; j < 4; j++)
                acc[i][j] = __builtin_amdgcn_mfma_f32_16x16x32_f16(af[i], bf[j], acc[i][j], 0, 0, 0);
        // drain regs -> next buffer (vmcnt wait here, after the MFMA phase)
        *(uint4*)&As[nxt][st8] = na0;
        *(uint4*)&As[nxt][2048 + st8] = na1;
        *(uint4*)&Bs[nxt][st8] = nb0;
        *(uint4*)&Bs[nxt][2048 + st8] = nb1;
        __syncthreads();   // lgkmcnt-only drain (no LDS-DMA outstanding)
    }
    {   // final k-step: compute on buffer 1
        v8h af[4], bf[4];
        #pragma unroll
        for (int i = 0; i < 4; i++)
            af[i] = *(const v8h*)&As[1][offA0 + i * 512];
        #pragma unroll
        for (int j = 0; j < 4; j++)
            bf[j] = *(const v8h*)&Bs[1][offB0 + j * 512];
        #pragma unroll
        for (int i = 0; i < 4; i++)
            #pragma unroll
            for (int j = 0; j < 4; j++)
                acc[i][j] = __builtin_amdgcn_mfma_f32_16x16x32_f16(af[i], bf[j], acc[i][j], 0, 0, 0);
    }

    // Epilogue: per-row top-3 over this wave's 64 cols, then LDS-merge the
    // two wave-columns so each block emits one chunk per row.
    // C layout: col=lane&15, row=quad*4+reg.
    const int cbase = c0 + wc * 64 + lm;
    #pragma unroll
    for (int i = 0; i < 4; i++) {
        #pragma unroll
        for (int r = 0; r < 4; r++) {
            float v1 = -1e30f, v2 = -1e30f, v3 = -1e30f;
            int i1 = 0x7fffffff, i2 = 0x7fffffff, i3 = 0x7fffffff;
            #pragma unroll
            for (int j = 0; j < 4; j++) {
                float v = acc[i][j][r];
                int cc = cbase + j * 16;
                INS3(v, cc);
            }
            #pragma unroll
            for (int m = 1; m < 16; m <<= 1) {
                float ov1 = __shfl_xor(v1, m, 64); int oi1 = __shfl_xor(i1, m, 64);
                float ov2 = __shfl_xor(v2, m, 64); int oi2 = __shfl_xor(i2, m, 64);
                float ov3 = __shfl_xor(v3, m, 64); int oi3 = __shfl_xor(i3, m, 64);
                INS3(ov1, oi1);
                INS3(ov2, oi2);
                INS3(ov3, oi3);
            }
            if (lm == 0) {
                int rr = i * 16 + quad * 4 + r;
                sV[wr][wc][rr][0] = v1; sV[wr][wc][rr][1] = v2; sV[wr][wc][rr][2] = v3;
                sI[wr][wc][rr][0] = i1; sI[wr][wc][rr][1] = i2; sI[wr][wc][rr][2] = i3;
            }
        }
    }
    __syncthreads();
    if (wc == 0) {
        float v1 = sV[wr][0][l][0], v2 = sV[wr][0][l][1], v3 = sV[wr][0][l][2];
        int i1 = sI[wr][0][l][0], i2 = sI[wr][0][l][1], i3 = sI[wr][0][l][2];
        float b1 = sV[wr][1][l][0], b2 = sV[wr][1][l][1], b3 = sV[wr][1][l][2];
        int c1 = sI[wr][1][l][0], c2 = sI[wr][1][l][1], c3 = sI[wr][1][l][2];
        INS3(b1, c1);
        INS3(b2, c2);
        INS3(b3, c3);
        size_t o = (size_t)by * NROWS + (r0 + wr * 64 + l);
        pV1[o] = v1; pV2[o] = v2; pV3[o] = v3;
        pI1[o] = i1; pI2[o] = i2; pI3[o] = i3;
    }
}

__global__ __launch_bounds__(256) void reduceKernel(
    const float* __restrict__ pV1, const float* __restrict__ pV2,
    const float* __restrict__ pV3, const int* __restrict__ pI1,
    const int* __restrict__ pI2, const int* __restrict__ pI3,
    int* __restrict__ bestIdx, int* __restrict__ flagRows,
    int* __restrict__ flagC2, int* __restrict__ flagC3,
    int* __restrict__ flagCnt, float* __restrict__ blkSum) {
    int t = threadIdx.x;
    int row = blockIdx.x * 256 + t;
    float v1 = -1e30f, v2 = -1e30f, v3 = -1e30f;
    int i1 = 0x7fffffff, i2 = 0x7fffffff, i3 = 0x7fffffff;
    for (int c = 0; c < NCH; c++) {
        size_t o = (size_t)c * NROWS + row;
        float a1 = pV1[o], a2 = pV2[o], a3 = pV3[o];
        int b1 = pI1[o], b2 = pI2[o], b3 = pI3[o];
        INS3(a1, b1);
        INS3(a2, b2);
        INS3(a3, b3);
    }
    bestIdx[row] = i1;
    if (v1 - v2 < EPS) {
        int s = atomicAdd(flagCnt, 1);
        flagRows[s] = row; flagC2[s] = i2; flagC3[s] = i3;
    }
    double sum = 1.0 - (double)v1;
    __shared__ double sh[4];
    #pragma unroll
    for (int off = 32; off; off >>= 1) sum += __shfl_down(sum, off, 64);
    if ((t & 63) == 0) sh[t >> 6] = sum;
    __syncthreads();
    if (t == 0) blkSum[blockIdx.x] = (float)(sh[0] + sh[1] + sh[2] + sh[3]);
}

// Exact fp64 re-check of top-3 candidates for near-tie rows; one wave per row.
__global__ __launch_bounds__(256) void refineKernel(
    const _Float16* __restrict__ Xh, const _Float16* __restrict__ Xl,
    const _Float16* __restrict__ Yh, const _Float16* __restrict__ Yl,
    int* __restrict__ bestIdx, const int* __restrict__ flagRows,
    const int* __restrict__ flagC2, const int* __restrict__ flagC3,
    const int* __restrict__ flagCnt) {
    int n = *flagCnt;
    int wave = (blockIdx.x << 2) + (threadIdx.x >> 6);
    int ln = threadIdx.x & 63;
    for (int fi = wave; fi < n; fi += gridDim.x * 4) {
        int row = flagRows[fi];
        int cand[3];
        cand[0] = bestIdx[row]; cand[1] = flagC2[fi]; cand[2] = flagC3[fi];
        double d[3];
        #pragma unroll
        for (int c = 0; c < 3; c++) {
            double p = 0.0;
            int yr = cand[c];
            #pragma unroll
            for (int q = 0; q < 16; q++) {
                int k = (ln << 4) + q;
                float xv = (float)Xh[(size_t)row * KY + k] + (float)Xl[(size_t)row * KY + k];
                float yv = (float)Yh[(size_t)yr * KY + k] + (float)Yl[(size_t)yr * KY + k];
                p += (double)xv * yv;
            }
            #pragma unroll
            for (int m = 1; m < 64; m <<= 1) p += __shfl_xor(p, m, 64);
            d[c] = p;
        }
        if (ln == 0) {
            int bi = cand[0]; double bv = d[0];
            #pragma unroll
            for (int c = 1; c < 3; c++) {
                if (d[c] > bv || (d[c] == bv && cand[c] < bi)) { bv = d[c]; bi = cand[c]; }
            }
            bestIdx[row] = bi;
        }
    }
}

// new_x gather (hi+lo reconstruct ~ fp32 codebook) + loss finalize.
__global__ __launch_bounds__(256) void gatherKernel(
    const _Float16* __restrict__ Yh, const _Float16* __restrict__ Yl,
    const int* __restrict__ bestIdx, const float* __restrict__ blkSum,
    float* __restrict__ out) {
    int t = threadIdx.x;
    if (blockIdx.x == 0 && t == 0) {
        double s = 0.0;
        for (int i = 0; i < 32; i++) s += (double)blkSum[i];
        out[0] = (float)(s / 8192.0);
    }
    int g = (blockIdx.x * 256 + t) << 2;
    int b = g >> 20, wq = (g >> 13) & 127, hq = (g >> 6) & 127, d = g & 63;
    int row = (b << 10) + ((wq >> 2) << 5) + (hq >> 2);
    int f = ((wq & 3) << 8) + ((hq & 3) << 6) + d;
    size_t base = (size_t)bestIdx[row] * KY + f;
    const _Float16* ph = &Yh[base];
    const _Float16* pl = &Yl[base];
    out[1 + g + 0] = (float)ph[0] + (float)pl[0];
    out[1 + g + 1] = (float)ph[1] + (float)pl[1];
    out[1 + g + 2] = (float)ph[2] + (float)pl[2];
    out[1 + g + 3] = (float)ph[3] + (float)pl[3];
}

extern "C" void kernel_launch(void* const* d_in, const int* in_sizes, int n_in,
                              void* d_out, int out_size, void* d_ws, size_t ws_size,
                              hipStream_t stream) {
    const float* x = (const float*)d_in[0];
    const float* y = (const float*)d_in[1];
    float* out = (float*)d_out;
    char* ws = (char*)d_ws;
    _Float16* Xh  = (_Float16*)(ws);
    _Float16* Xl  = (_Float16*)(ws + 16777216u);
    _Float16* Yh  = (_Float16*)(ws + 33554432u);
    _Float16* Yl  = (_Float16*)(ws + 50331648u);
    float* pV1    = (float*)(ws + 67108864u);
    float* pV2    = (float*)(ws + 69206016u);
    float* pV3    = (float*)(ws + 71303168u);
    int*   pI1    = (int*)  (ws + 73400320u);
    int*   pI2    = (int*)  (ws + 75497472u);
    int*   pI3    = (int*)  (ws + 77594624u);
    int* bestIdx  = (int*)  (ws + 79691776u);
    int* flagRows = (int*)  (ws + 79724544u);
    int* flagC2   = (int*)  (ws + 79757312u);
    int* flagC3   = (int*)  (ws + 79790080u);
    int* flagCnt  = (int*)  (ws + 79822848u);
    float* blkSum = (float*)(ws + 79822976u);

    normSplitKernel<<<4096, 256, 0, stream>>>(x, y, Xh, Xl, Yh, Yl, flagCnt);
    simKernel<<<dim3(64, 64), 256, 0, stream>>>(Xh, Yh, pV1, pV2, pV3, pI1, pI2, pI3);
    reduceKernel<<<32, 256, 0, stream>>>(pV1, pV2, pV3, pI1, pI2, pI3,
                                         bestIdx, flagRows, flagC2, flagC3, flagCnt, blkSum);
    refineKernel<<<64, 256, 0, stream>>>(Xh, Xl, Yh, Yl, bestIdx,
                                         flagRows, flagC2, flagC3, flagCnt);
    gatherKernel<<<8192, 256, 0, stream>>>(Yh, Yl, bestIdx, blkSum, out);
}